// Round 6
// baseline (595.675 us; speedup 1.0000x reference)
//
#include <hip/hip_runtime.h>

#define N_NODES 50000
#define N_EDGES 640000
#define HID 128
#define EF 16
#define NLAYERS 3
#define CHUNK 32
#define SCAN_BLOCKS 196  // ceil(50000/256)

typedef __attribute__((ext_vector_type(8))) short short8;
typedef __attribute__((ext_vector_type(4))) float f32x4;
typedef __attribute__((ext_vector_type(2))) float f32x2;

__device__ __forceinline__ unsigned short f2bf(float f) {
  unsigned int u = __float_as_uint(f);
  u = u + 0x7FFFu + ((u >> 16) & 1u);  // RNE
  return (unsigned short)(u >> 16);
}

// 8-lane butterfly sum via DPP: xor1, xor2 (quad_perm), then half-row mirror.
// Reduces within each aligned group of 8 lanes (one head).
__device__ __forceinline__ float dpp_hadd8(float v) {
  int x;
  x = __builtin_amdgcn_update_dpp(0, __float_as_int(v), 0xB1, 0xF, 0xF, true);
  v += __int_as_float(x);
  x = __builtin_amdgcn_update_dpp(0, __float_as_int(v), 0x4E, 0xF, 0xF, true);
  v += __int_as_float(x);
  x = __builtin_amdgcn_update_dpp(0, __float_as_int(v), 0x141, 0xF, 0xF, true);
  v += __int_as_float(x);
  return v;
}

// channel j = h*16+c -> paired slot: lane l = h*8 + (c&7) holds halves c>>3.
// slot(j) = l*2 + (c>>3). Both of a lane's channels share head h = l>>3.
__device__ __forceinline__ int pslot(int j) {
  return (((j >> 4) * 8 + (j & 7)) << 1) + ((j >> 3) & 1);
}

// Mt[l][k][slot(j)] = sum_i Wt[k,i] * We[l][i,j]   (16x128 per layer, paired cols)
// ct[l][slot(j)]    = sum_i bt[i]  * We[l][i,j]
__global__ __launch_bounds__(256) void k_prep(const float* __restrict__ Wt,
                                              const float* __restrict__ bt,
                                              const float* __restrict__ We,
                                              float* __restrict__ Mt,
                                              float* __restrict__ ct) {
  int id = blockIdx.x * 256 + threadIdx.x;
  const int total = NLAYERS * (EF + 1) * HID;
  if (id >= total) return;
  int l = id / ((EF + 1) * HID);
  int r = id % ((EF + 1) * HID);
  int row = r / HID;
  int j = r % HID;
  const float* Wel = We + l * HID * HID;
  float s = 0.f;
  if (row < EF) {
    const float* wtr = Wt + row * HID;
    for (int i = 0; i < HID; ++i) s += wtr[i] * Wel[i * HID + j];
    Mt[(l * EF + row) * HID + pslot(j)] = s;
  } else {
    for (int i = 0; i < HID; ++i) s += bt[i] * Wel[i * HID + j];
    ct[l * HID + pslot(j)] = s;
  }
}

// x0 (fp32) -> bf16
__global__ __launch_bounds__(256) void k_cvtx(const float* __restrict__ x,
                                              unsigned short* __restrict__ xbf) {
  int id = blockIdx.x * 256 + threadIdx.x;  // one per 8 elements
  const int total = N_NODES * HID / 8;
  if (id >= total) return;
  const float4* p = (const float4*)(x + id * 8);
  float4 a = p[0], b = p[1];
  unsigned short o[8] = {f2bf(a.x), f2bf(a.y), f2bf(a.z), f2bf(a.w),
                         f2bf(b.x), f2bf(b.y), f2bf(b.z), f2bf(b.w)};
  *(uint4*)(xbf + id * 8) = *(uint4*)o;
}

// WT_bf[l][s][n][k] = bf16( W_s[l][k][n] ),  s=0 -> Wl, s=1 -> Wr
__global__ __launch_bounds__(256) void k_cvtw(const float* __restrict__ Wl,
                                              const float* __restrict__ Wr,
                                              unsigned short* __restrict__ WT) {
  int id = blockIdx.x * 256 + threadIdx.x;
  const int total = NLAYERS * 2 * HID * HID;
  if (id >= total) return;
  int k = id & (HID - 1);
  int n = (id >> 7) & (HID - 1);
  int s = (id >> 14) & 1;
  int l = id >> 15;
  const float* W = (s == 0 ? Wl : Wr) + (size_t)l * HID * HID;
  WT[id] = f2bf(W[k * HID + n]);
}

__global__ __launch_bounds__(256) void k_zero(int* __restrict__ counts, int* __restrict__ fill) {
  int id = blockIdx.x * 256 + threadIdx.x;
  if (id < N_NODES) { counts[id] = 0; fill[id] = 0; }
}

__global__ __launch_bounds__(256) void k_hist(const int* __restrict__ dst, int* __restrict__ counts) {
  int e = blockIdx.x * 256 + threadIdx.x;
  if (e < N_EDGES) atomicAdd(&counts[dst[e]], 1);
}

__global__ __launch_bounds__(256) void k_scan1(const int* __restrict__ counts,
                                               int* __restrict__ rowptr,
                                               int* __restrict__ bsum) {
  __shared__ int sc[256];
  int t = threadIdx.x;
  int i = blockIdx.x * 256 + t;
  int v = (i < N_NODES) ? counts[i] : 0;
  sc[t] = v;
  __syncthreads();
  for (int off = 1; off < 256; off <<= 1) {
    int u = 0;
    if (t >= off) u = sc[t - off];
    __syncthreads();
    sc[t] += u;
    __syncthreads();
  }
  if (i < N_NODES) rowptr[i] = sc[t] - v;  // block-local exclusive
  if (t == 255) bsum[blockIdx.x] = sc[255];
}

__global__ __launch_bounds__(256) void k_scan2(int* __restrict__ bsum) {
  __shared__ int sc[256];
  int t = threadIdx.x;
  int v = (t < SCAN_BLOCKS) ? bsum[t] : 0;
  sc[t] = v;
  __syncthreads();
  for (int off = 1; off < 256; off <<= 1) {
    int u = 0;
    if (t >= off) u = sc[t - off];
    __syncthreads();
    sc[t] += u;
    __syncthreads();
  }
  bsum[t] = sc[t] - v;  // exclusive block offsets
}

__global__ __launch_bounds__(256) void k_scan3(int* __restrict__ rowptr, const int* __restrict__ bsum) {
  int t = threadIdx.x;
  int i = blockIdx.x * 256 + t;
  if (i < N_NODES) rowptr[i] += bsum[blockIdx.x];
  if (i == 0) rowptr[N_NODES] = N_EDGES;
}

// Scatter edges into dst-sorted order; also copy edge_attr rows so the hot
// loop reads them fully sequentially (no 2x cacheline over-fetch).
__global__ __launch_bounds__(256) void k_fill(const int* __restrict__ src,
                                              const int* __restrict__ dst,
                                              const int* __restrict__ rowptr,
                                              int* __restrict__ fill,
                                              int* __restrict__ ssrc,
                                              const float* __restrict__ eattr,
                                              float* __restrict__ easrt) {
  int e = blockIdx.x * 256 + threadIdx.x;
  if (e >= N_EDGES) return;
  int d = dst[e];
  int pos = atomicAdd(&fill[d], 1);
  int idx = rowptr[d] + pos;
  ssrc[idx] = src[e];
  const float4* pe = (const float4*)(eattr + (size_t)e * EF);
  float4* po = (float4*)(easrt + (size_t)idx * EF);
#pragma unroll
  for (int q = 0; q < 4; ++q) po[q] = pe[q];
}

// bf16 MFMA node GEMM: out_s = x @ W_s + b_s, channel-PAIRED layout, both
// outputs stored as bf16 (xl: gather table; xr: logit-only -> bf16 safe).
__global__ __launch_bounds__(256) void k_gemm_mfma(const unsigned short* __restrict__ xbf,
                                                   const unsigned short* __restrict__ WTl,  // layer base: [2][128][128]
                                                   const float* __restrict__ bl,
                                                   const float* __restrict__ br,
                                                   unsigned short* __restrict__ xlb,  // paired bf16
                                                   unsigned short* __restrict__ xrb) {  // paired bf16
  __shared__ short As[64 * 136];
  __shared__ short Bs[128 * 136];
  int t = threadIdx.x;
  int s = blockIdx.y;
  int row0 = blockIdx.x * 64;

  // stage A: 64 rows x 128 bf16, 16B chunks
  const uint4* gx = (const uint4*)xbf;
#pragma unroll
  for (int p = 0; p < 4; ++p) {
    int c = t + p * 256;
    int row = c >> 4, col16 = c & 15;
    int grow = row0 + row;
    if (grow >= N_NODES) grow = N_NODES - 1;
    uint4 v = gx[grow * 16 + col16];
    *(uint4*)(&As[row * 136 + col16 * 8]) = v;
  }
  // stage B: 128 rows (n) x 128 bf16 of WT[s]
  const uint4* gw = (const uint4*)WTl;
#pragma unroll
  for (int p = 0; p < 8; ++p) {
    int c = t + p * 256;
    int row = c >> 4, col16 = c & 15;
    uint4 v = gw[s * 2048 + row * 16 + col16];
    *(uint4*)(&Bs[row * 136 + col16 * 8]) = v;
  }
  __syncthreads();

  int lane = t & 63, w = t >> 6;
  int quad = lane >> 4, lm = lane & 15;
  f32x4 acc[4][2];
#pragma unroll
  for (int mf = 0; mf < 4; ++mf)
#pragma unroll
    for (int nf = 0; nf < 2; ++nf) acc[mf][nf] = (f32x4)(0.f);

#pragma unroll
  for (int ks = 0; ks < 4; ++ks) {
    short8 af[4], bf[2];
#pragma unroll
    for (int mf = 0; mf < 4; ++mf)
      af[mf] = *(short8*)(&As[(mf * 16 + lm) * 136 + ks * 32 + quad * 8]);
#pragma unroll
    for (int nf = 0; nf < 2; ++nf)
      bf[nf] = *(short8*)(&Bs[(w * 32 + nf * 16 + lm) * 136 + ks * 32 + quad * 8]);
#pragma unroll
    for (int mf = 0; mf < 4; ++mf)
#pragma unroll
      for (int nf = 0; nf < 2; ++nf)
        acc[mf][nf] = __builtin_amdgcn_mfma_f32_16x16x32_bf16(af[mf], bf[nf], acc[mf][nf], 0, 0, 0);
  }

  const float* bias = (s == 0) ? bl : br;
  unsigned short* out = (s == 0) ? xlb : xrb;
#pragma unroll
  for (int nf = 0; nf < 2; ++nf) {
    int n = w * 32 + nf * 16 + lm;
    float bv = bias[n];
    int slot = pslot(n);
#pragma unroll
    for (int mf = 0; mf < 4; ++mf) {
#pragma unroll
      for (int r = 0; r < 4; ++r) {
        int grow = row0 + mf * 16 + quad * 4 + r;
        if (grow < N_NODES) out[(size_t)grow * HID + slot] = f2bf(acc[mf][nf][r] + bv);
      }
    }
  }
}

// 4 waves per block, one destination node per wave (per-wave LDS regions).
// All waves loop to the block-max trip count so __syncthreads() is uniform.
// Lane l owns channels j0=(l>>3)*16+(l&7) and j0+8 (same head -> one 8-lane
// DPP reduce + one exp per edge). xl,xr gathered as paired bf16 dwords.
__global__ __launch_bounds__(256) void k_fused(const float* __restrict__ xin,
                                               const unsigned int* __restrict__ xlb,  // paired bf16
                                               const unsigned int* __restrict__ xrb,  // paired bf16
                                               const int* __restrict__ rowptr,
                                               const int* __restrict__ ssrc,
                                               const float* __restrict__ easrt,  // dst-sorted [E][16]
                                               const float* __restrict__ Mt,   // paired cols
                                               const float* __restrict__ ct,   // paired
                                               const float* __restrict__ att,
                                               const float* __restrict__ bias_o,
                                               const float* __restrict__ lng,
                                               const float* __restrict__ lnb,
                                               float* __restrict__ xout,
                                               unsigned short* __restrict__ xbf_out) {
  __shared__ float ea_s[4][CHUNK][EF];
  __shared__ int src_s[4][CHUNK];
  __shared__ int trips_s[4];
  int tid = threadIdx.x;
  int w = tid >> 6, l = tid & 63;
  int n = blockIdx.x * 4 + w;  // N_NODES % 4 == 0 -> always valid
  int j0 = (l >> 3) * 16 + (l & 7), j1 = j0 + 8;

  f32x2 mtp[EF];
#pragma unroll
  for (int k = 0; k < EF; ++k) mtp[k] = *(const f32x2*)(&Mt[k * HID + l * 2]);
  unsigned int ur = xrb[(size_t)n * 64 + l];
  f32x2 base;
  base.x = __uint_as_float(ur << 16);
  base.y = __uint_as_float(ur & 0xFFFF0000u);
  base += *(const f32x2*)(&ct[l * 2]);
  f32x2 attp = {att[j0], att[j1]};
  int beg = rowptr[n], end = rowptr[n + 1];
  int trips = (end - beg + CHUNK - 1) >> 5;
  if (l == 0) trips_s[w] = trips;
  __syncthreads();
  int maxtrips = max(max(trips_s[0], trips_s[1]), max(trips_s[2], trips_s[3]));

  f32x2 acc = {0.f, 0.f};
  float denom = 0.f;

  for (int t = 0; t < maxtrips; ++t) {
    __syncthreads();  // prev trip's reads done before restage
    int c0 = beg + t * CHUNK;
    int cnt = min(CHUNK, end - c0);
    if (t < trips) {
      if (l < cnt) src_s[w][l] = ssrc[c0 + l];
      for (int q = l; q < cnt * 4; q += 64) {
        int i = q >> 2, part = q & 3;
        *(float4*)(&ea_s[w][i][part * 4]) =
            *(const float4*)(easrt + (size_t)(c0 + i) * EF + part * 4);
      }
    }
    __syncthreads();
    if (t < trips) {
      auto edge = [&](int i, unsigned int u) {
        f32x2 xls;
        xls.x = __uint_as_float(u << 16);
        xls.y = __uint_as_float(u & 0xFFFF0000u);
        f32x2 m = base + xls;
#pragma unroll
        for (int k = 0; k < EF; ++k) m += ea_s[w][i][k] * mtp[k];
        // leaky_relu(m, 0.2) = 0.6*m + 0.4*|m|
        f32x2 am = {__int_as_float(__float_as_int(m.x) & 0x7FFFFFFF),
                    __int_as_float(__float_as_int(m.y) & 0x7FFFFFFF)};
        m = 0.6f * m + 0.4f * am;
        f32x2 v2 = m * attp;
        float vs = dpp_hadd8(v2.x + v2.y);  // head logit (8 lanes share head)
        float p = __expf(vs);               // logits small: no max-subtract
        denom += p;
        acc += xls * p;
      };
      int i = 0;
      for (; i + 2 <= cnt; i += 2) {
        int s0 = src_s[w][i], s1 = src_s[w][i + 1];
        unsigned int u0 = xlb[(size_t)s0 * 64 + l];  // both issued before use
        unsigned int u1 = xlb[(size_t)s1 * 64 + l];
        edge(i, u0);
        edge(i + 1, u1);
      }
      if (i < cnt) edge(i, xlb[(size_t)src_s[w][i] * 64 + l]);
    }
  }

  f32x2 outp;
  float inv = 1.f / (denom + 1e-16f);
  outp.x = acc.x * inv + bias_o[j0];
  outp.y = acc.y * inv + bias_o[j1];
  // LayerNorm over 128 channels: pair-sum then 64-lane butterfly (per wave)
  float s1 = outp.x + outp.y;
  float s2 = outp.x * outp.x + outp.y * outp.y;
#pragma unroll
  for (int mask = 1; mask <= 32; mask <<= 1) {
    s1 += __shfl_xor(s1, mask);
    s2 += __shfl_xor(s2, mask);
  }
  float mu = s1 * (1.f / 128.f);
  float var = s2 * (1.f / 128.f) - mu * mu;
  float rs = rsqrtf(var + 1e-5f);
  float y0 = lng[j0] * (outp.x - mu) * rs + lnb[j0];
  float y1 = lng[j1] * (outp.y - mu) * rs + lnb[j1];
  float r0 = fmaxf(y0, 0.f) + xin[(size_t)n * HID + j0];
  float r1 = fmaxf(y1, 0.f) + xin[(size_t)n * HID + j1];
  xout[(size_t)n * HID + j0] = r0;
  xout[(size_t)n * HID + j1] = r1;
  xbf_out[(size_t)n * HID + j0] = f2bf(r0);
  xbf_out[(size_t)n * HID + j1] = f2bf(r1);
}

extern "C" void kernel_launch(void* const* d_in, const int* in_sizes, int n_in,
                              void* d_out, int out_size, void* d_ws, size_t ws_size,
                              hipStream_t stream) {
  const float* x0    = (const float*)d_in[0];
  const int*   eidx  = (const int*)d_in[2];
  const float* eattr = (const float*)d_in[3];
  const float* Wt    = (const float*)d_in[4];
  const float* bt    = (const float*)d_in[5];
  const float* Wl    = (const float*)d_in[6];
  const float* bl    = (const float*)d_in[7];
  const float* Wr    = (const float*)d_in[8];
  const float* br    = (const float*)d_in[9];
  const float* We    = (const float*)d_in[10];
  const float* att   = (const float*)d_in[11];
  const float* bo    = (const float*)d_in[12];
  const float* lng   = (const float*)d_in[13];
  const float* lnb   = (const float*)d_in[14];
  float* out = (float*)d_out;
  const int* src = eidx;
  const int* dst = eidx + N_EDGES;

  char* ws = (char*)d_ws;
  size_t off = 0;
  auto alloc = [&](size_t bytes) {
    char* p = ws + off;
    off += (bytes + 255) & ~(size_t)255;
    return p;
  };
  float* Mt   = (float*)alloc((size_t)NLAYERS * EF * HID * 4);
  float* ct   = (float*)alloc((size_t)NLAYERS * HID * 4);
  int* counts = (int*)alloc((size_t)N_NODES * 4);
  int* rowptr = (int*)alloc((size_t)(N_NODES + 1) * 4);
  int* bsum   = (int*)alloc(256 * 4);
  int* fill   = (int*)alloc((size_t)N_NODES * 4);
  int* ssrc   = (int*)alloc((size_t)N_EDGES * 4);
  float* easrt = (float*)alloc((size_t)N_EDGES * EF * 4);
  unsigned short* xlb = (unsigned short*)alloc((size_t)N_NODES * HID * 2);
  unsigned short* xrb = (unsigned short*)alloc((size_t)N_NODES * HID * 2);
  float* xbuf = (float*)alloc((size_t)N_NODES * HID * 4);
  unsigned short* xbf = (unsigned short*)alloc((size_t)N_NODES * HID * 2);
  unsigned short* WTb = (unsigned short*)alloc((size_t)NLAYERS * 2 * HID * HID * 2);

  hipLaunchKernelGGL(k_prep, dim3(26), dim3(256), 0, stream, Wt, bt, We, Mt, ct);
  hipLaunchKernelGGL(k_cvtx, dim3((N_NODES * HID / 8 + 255) / 256), dim3(256), 0, stream, x0, xbf);
  hipLaunchKernelGGL(k_cvtw, dim3((NLAYERS * 2 * HID * HID + 255) / 256), dim3(256), 0, stream, Wl, Wr, WTb);
  hipLaunchKernelGGL(k_zero, dim3(SCAN_BLOCKS), dim3(256), 0, stream, counts, fill);
  hipLaunchKernelGGL(k_hist, dim3((N_EDGES + 255) / 256), dim3(256), 0, stream, dst, counts);
  hipLaunchKernelGGL(k_scan1, dim3(SCAN_BLOCKS), dim3(256), 0, stream, counts, rowptr, bsum);
  hipLaunchKernelGGL(k_scan2, dim3(1), dim3(256), 0, stream, bsum);
  hipLaunchKernelGGL(k_scan3, dim3(SCAN_BLOCKS), dim3(256), 0, stream, rowptr, bsum);
  hipLaunchKernelGGL(k_fill, dim3((N_EDGES + 255) / 256), dim3(256), 0, stream,
                     src, dst, rowptr, fill, ssrc, eattr, easrt);

  for (int l = 0; l < NLAYERS; ++l) {
    const float* xin = (l == 0) ? x0 : (const float*)xbuf;
    float* xout = (l == NLAYERS - 1) ? out : xbuf;
    hipLaunchKernelGGL(k_gemm_mfma, dim3((N_NODES + 63) / 64, 2), dim3(256), 0, stream,
                       xbf, WTb + (size_t)l * 2 * HID * HID, bl + l * HID, br + l * HID, xlb, xrb);
    hipLaunchKernelGGL(k_fused, dim3(N_NODES / 4), dim3(256), 0, stream,
                       xin, (const unsigned int*)xlb, (const unsigned int*)xrb,
                       rowptr, ssrc, easrt,
                       Mt + (size_t)l * EF * HID, ct + l * HID, att + l * HID,
                       bo + l * HID, lng + l * HID, lnb + l * HID, xout, xbf);
  }
}

// Round 7
// 582.770 us; speedup vs baseline: 1.0221x; 1.0221x over previous
//
#include <hip/hip_runtime.h>

#define N_NODES 50000
#define N_EDGES 640000
#define HID 128
#define EF 16
#define NLAYERS 3
#define CHUNK 32
#define SCAN_BLOCKS 196  // ceil(50000/256)

typedef __attribute__((ext_vector_type(8))) short short8;
typedef __attribute__((ext_vector_type(4))) float f32x4;
typedef __attribute__((ext_vector_type(2))) float f32x2;

__device__ __forceinline__ unsigned short f2bf(float f) {
  unsigned int u = __float_as_uint(f);
  u = u + 0x7FFFu + ((u >> 16) & 1u);  // RNE
  return (unsigned short)(u >> 16);
}

// 8-lane butterfly sum via DPP: xor1, xor2 (quad_perm), then half-row mirror.
// Reduces within each aligned group of 8 lanes (one head).
__device__ __forceinline__ float dpp_hadd8(float v) {
  int x;
  x = __builtin_amdgcn_update_dpp(0, __float_as_int(v), 0xB1, 0xF, 0xF, true);
  v += __int_as_float(x);
  x = __builtin_amdgcn_update_dpp(0, __float_as_int(v), 0x4E, 0xF, 0xF, true);
  v += __int_as_float(x);
  x = __builtin_amdgcn_update_dpp(0, __float_as_int(v), 0x141, 0xF, 0xF, true);
  v += __int_as_float(x);
  return v;
}

// channel j = h*16+c -> paired slot: lane l = h*8 + (c&7) holds halves c>>3.
// slot(j) = l*2 + (c>>3). Both of a lane's channels share head h = l>>3.
__device__ __forceinline__ int pslot(int j) {
  return (((j >> 4) * 8 + (j & 7)) << 1) + ((j >> 3) & 1);
}

// Mt[l][k][slot(j)] = sum_i Wt[k,i] * We[l][i,j]   (16x128 per layer, paired cols)
// ct[l][slot(j)]    = sum_i bt[i]  * We[l][i,j]
__global__ __launch_bounds__(256) void k_prep(const float* __restrict__ Wt,
                                              const float* __restrict__ bt,
                                              const float* __restrict__ We,
                                              float* __restrict__ Mt,
                                              float* __restrict__ ct) {
  int id = blockIdx.x * 256 + threadIdx.x;
  const int total = NLAYERS * (EF + 1) * HID;
  if (id >= total) return;
  int l = id / ((EF + 1) * HID);
  int r = id % ((EF + 1) * HID);
  int row = r / HID;
  int j = r % HID;
  const float* Wel = We + l * HID * HID;
  float s = 0.f;
  if (row < EF) {
    const float* wtr = Wt + row * HID;
    for (int i = 0; i < HID; ++i) s += wtr[i] * Wel[i * HID + j];
    Mt[(l * EF + row) * HID + pslot(j)] = s;
  } else {
    for (int i = 0; i < HID; ++i) s += bt[i] * Wel[i * HID + j];
    ct[l * HID + pslot(j)] = s;
  }
}

// x0 (fp32) -> bf16
__global__ __launch_bounds__(256) void k_cvtx(const float* __restrict__ x,
                                              unsigned short* __restrict__ xbf) {
  int id = blockIdx.x * 256 + threadIdx.x;  // one per 8 elements
  const int total = N_NODES * HID / 8;
  if (id >= total) return;
  const float4* p = (const float4*)(x + id * 8);
  float4 a = p[0], b = p[1];
  unsigned short o[8] = {f2bf(a.x), f2bf(a.y), f2bf(a.z), f2bf(a.w),
                         f2bf(b.x), f2bf(b.y), f2bf(b.z), f2bf(b.w)};
  *(uint4*)(xbf + id * 8) = *(uint4*)o;
}

// WT_bf[l][s][n][k] = bf16( W_s[l][k][n] ),  s=0 -> Wl, s=1 -> Wr
__global__ __launch_bounds__(256) void k_cvtw(const float* __restrict__ Wl,
                                              const float* __restrict__ Wr,
                                              unsigned short* __restrict__ WT) {
  int id = blockIdx.x * 256 + threadIdx.x;
  const int total = NLAYERS * 2 * HID * HID;
  if (id >= total) return;
  int k = id & (HID - 1);
  int n = (id >> 7) & (HID - 1);
  int s = (id >> 14) & 1;
  int l = id >> 15;
  const float* W = (s == 0 ? Wl : Wr) + (size_t)l * HID * HID;
  WT[id] = f2bf(W[k * HID + n]);
}

__global__ __launch_bounds__(256) void k_zero(int* __restrict__ counts, int* __restrict__ fill) {
  int id = blockIdx.x * 256 + threadIdx.x;
  if (id < N_NODES) { counts[id] = 0; fill[id] = 0; }
}

__global__ __launch_bounds__(256) void k_hist(const int* __restrict__ dst, int* __restrict__ counts) {
  int e = blockIdx.x * 256 + threadIdx.x;
  if (e < N_EDGES) atomicAdd(&counts[dst[e]], 1);
}

__global__ __launch_bounds__(256) void k_scan1(const int* __restrict__ counts,
                                               int* __restrict__ rowptr,
                                               int* __restrict__ bsum) {
  __shared__ int sc[256];
  int t = threadIdx.x;
  int i = blockIdx.x * 256 + t;
  int v = (i < N_NODES) ? counts[i] : 0;
  sc[t] = v;
  __syncthreads();
  for (int off = 1; off < 256; off <<= 1) {
    int u = 0;
    if (t >= off) u = sc[t - off];
    __syncthreads();
    sc[t] += u;
    __syncthreads();
  }
  if (i < N_NODES) rowptr[i] = sc[t] - v;  // block-local exclusive
  if (t == 255) bsum[blockIdx.x] = sc[255];
}

__global__ __launch_bounds__(256) void k_scan2(int* __restrict__ bsum) {
  __shared__ int sc[256];
  int t = threadIdx.x;
  int v = (t < SCAN_BLOCKS) ? bsum[t] : 0;
  sc[t] = v;
  __syncthreads();
  for (int off = 1; off < 256; off <<= 1) {
    int u = 0;
    if (t >= off) u = sc[t - off];
    __syncthreads();
    sc[t] += u;
    __syncthreads();
  }
  bsum[t] = sc[t] - v;  // exclusive block offsets
}

__global__ __launch_bounds__(256) void k_scan3(int* __restrict__ rowptr, const int* __restrict__ bsum) {
  int t = threadIdx.x;
  int i = blockIdx.x * 256 + t;
  if (i < N_NODES) rowptr[i] += bsum[blockIdx.x];
  if (i == 0) rowptr[N_NODES] = N_EDGES;
}

// Scatter edges into dst-sorted order; also copy edge_attr rows so the hot
// loop reads them fully sequentially (no 2x cacheline over-fetch).
__global__ __launch_bounds__(256) void k_fill(const int* __restrict__ src,
                                              const int* __restrict__ dst,
                                              const int* __restrict__ rowptr,
                                              int* __restrict__ fill,
                                              int* __restrict__ ssrc,
                                              const float* __restrict__ eattr,
                                              float* __restrict__ easrt) {
  int e = blockIdx.x * 256 + threadIdx.x;
  if (e >= N_EDGES) return;
  int d = dst[e];
  int pos = atomicAdd(&fill[d], 1);
  int idx = rowptr[d] + pos;
  ssrc[idx] = src[e];
  const float4* pe = (const float4*)(eattr + (size_t)e * EF);
  float4* po = (float4*)(easrt + (size_t)idx * EF);
#pragma unroll
  for (int q = 0; q < 4; ++q) po[q] = pe[q];
}

// bf16 MFMA node GEMM: out_s = x @ W_s + b_s, channel-PAIRED layout, both
// outputs stored as bf16 (xl: gather table; xr: logit-only -> bf16 safe).
__global__ __launch_bounds__(256) void k_gemm_mfma(const unsigned short* __restrict__ xbf,
                                                   const unsigned short* __restrict__ WTl,  // layer base: [2][128][128]
                                                   const float* __restrict__ bl,
                                                   const float* __restrict__ br,
                                                   unsigned short* __restrict__ xlb,  // paired bf16
                                                   unsigned short* __restrict__ xrb) {  // paired bf16
  __shared__ short As[64 * 136];
  __shared__ short Bs[128 * 136];
  int t = threadIdx.x;
  int s = blockIdx.y;
  int row0 = blockIdx.x * 64;

  // stage A: 64 rows x 128 bf16, 16B chunks
  const uint4* gx = (const uint4*)xbf;
#pragma unroll
  for (int p = 0; p < 4; ++p) {
    int c = t + p * 256;
    int row = c >> 4, col16 = c & 15;
    int grow = row0 + row;
    if (grow >= N_NODES) grow = N_NODES - 1;
    uint4 v = gx[grow * 16 + col16];
    *(uint4*)(&As[row * 136 + col16 * 8]) = v;
  }
  // stage B: 128 rows (n) x 128 bf16 of WT[s]
  const uint4* gw = (const uint4*)WTl;
#pragma unroll
  for (int p = 0; p < 8; ++p) {
    int c = t + p * 256;
    int row = c >> 4, col16 = c & 15;
    uint4 v = gw[s * 2048 + row * 16 + col16];
    *(uint4*)(&Bs[row * 136 + col16 * 8]) = v;
  }
  __syncthreads();

  int lane = t & 63, w = t >> 6;
  int quad = lane >> 4, lm = lane & 15;
  f32x4 acc[4][2];
#pragma unroll
  for (int mf = 0; mf < 4; ++mf)
#pragma unroll
    for (int nf = 0; nf < 2; ++nf) acc[mf][nf] = (f32x4)(0.f);

#pragma unroll
  for (int ks = 0; ks < 4; ++ks) {
    short8 af[4], bf[2];
#pragma unroll
    for (int mf = 0; mf < 4; ++mf)
      af[mf] = *(short8*)(&As[(mf * 16 + lm) * 136 + ks * 32 + quad * 8]);
#pragma unroll
    for (int nf = 0; nf < 2; ++nf)
      bf[nf] = *(short8*)(&Bs[(w * 32 + nf * 16 + lm) * 136 + ks * 32 + quad * 8]);
#pragma unroll
    for (int mf = 0; mf < 4; ++mf)
#pragma unroll
      for (int nf = 0; nf < 2; ++nf)
        acc[mf][nf] = __builtin_amdgcn_mfma_f32_16x16x32_bf16(af[mf], bf[nf], acc[mf][nf], 0, 0, 0);
  }

  const float* bias = (s == 0) ? bl : br;
  unsigned short* out = (s == 0) ? xlb : xrb;
#pragma unroll
  for (int nf = 0; nf < 2; ++nf) {
    int n = w * 32 + nf * 16 + lm;
    float bv = bias[n];
    int slot = pslot(n);
#pragma unroll
    for (int mf = 0; mf < 4; ++mf) {
#pragma unroll
      for (int r = 0; r < 4; ++r) {
        int grow = row0 + mf * 16 + quad * 4 + r;
        if (grow < N_NODES) out[(size_t)grow * HID + slot] = f2bf(acc[mf][nf][r] + bv);
      }
    }
  }
}

// 4 waves per block, one destination node per wave — waves fully INDEPENDENT:
// each wave stages into its own LDS region and syncs only via the wave's own
// lgkmcnt (wave-synchronous LDS; no __syncthreads, no cross-wave coupling).
// Lane l owns channels j0=(l>>3)*16+(l&7) and j0+8 (same head -> one 8-lane
// DPP reduce + one exp per edge). xl,xr gathered as paired bf16 dwords.
__global__ __launch_bounds__(256) void k_fused(const float* __restrict__ xin,
                                               const unsigned int* __restrict__ xlb,  // paired bf16
                                               const unsigned int* __restrict__ xrb,  // paired bf16
                                               const int* __restrict__ rowptr,
                                               const int* __restrict__ ssrc,
                                               const float* __restrict__ easrt,  // dst-sorted [E][16]
                                               const float* __restrict__ Mt,   // paired cols
                                               const float* __restrict__ ct,   // paired
                                               const float* __restrict__ att,
                                               const float* __restrict__ bias_o,
                                               const float* __restrict__ lng,
                                               const float* __restrict__ lnb,
                                               float* __restrict__ xout,
                                               unsigned short* __restrict__ xbf_out) {
  __shared__ float ea_s[4][CHUNK][EF];
  __shared__ int src_s[4][CHUNK];
  int tid = threadIdx.x;
  int w = tid >> 6, l = tid & 63;
  int n = blockIdx.x * 4 + w;  // N_NODES % 4 == 0 -> always valid
  int j0 = (l >> 3) * 16 + (l & 7), j1 = j0 + 8;

  f32x2 mtp[EF];
#pragma unroll
  for (int k = 0; k < EF; ++k) mtp[k] = *(const f32x2*)(&Mt[k * HID + l * 2]);
  unsigned int ur = xrb[(size_t)n * 64 + l];
  f32x2 base;
  base.x = __uint_as_float(ur << 16);
  base.y = __uint_as_float(ur & 0xFFFF0000u);
  base += *(const f32x2*)(&ct[l * 2]);
  f32x2 attp = {att[j0], att[j1]};
  int beg = rowptr[n], end = rowptr[n + 1];

  f32x2 acc = {0.f, 0.f};
  float denom = 0.f;

  for (int c0 = beg; c0 < end; c0 += CHUNK) {
    int cnt = min(CHUNK, end - c0);
    // wave-private staging: intra-wave LDS RAW ordered by lgkmcnt (lockstep wave)
    if (l < cnt) src_s[w][l] = ssrc[c0 + l];
    for (int q = l; q < cnt * 4; q += 64) {
      int i = q >> 2, part = q & 3;
      *(float4*)(&ea_s[w][i][part * 4]) =
          *(const float4*)(easrt + (size_t)(c0 + i) * EF + part * 4);
    }

    auto edge = [&](int i, unsigned int u) {
      f32x2 xls;
      xls.x = __uint_as_float(u << 16);
      xls.y = __uint_as_float(u & 0xFFFF0000u);
      f32x2 m = base + xls;
#pragma unroll
      for (int k = 0; k < EF; ++k) m += ea_s[w][i][k] * mtp[k];
      // leaky_relu(m, 0.2) = 0.6*m + 0.4*|m|
      f32x2 am = {__int_as_float(__float_as_int(m.x) & 0x7FFFFFFF),
                  __int_as_float(__float_as_int(m.y) & 0x7FFFFFFF)};
      m = 0.6f * m + 0.4f * am;
      f32x2 v2 = m * attp;
      float vs = dpp_hadd8(v2.x + v2.y);  // head logit (8 lanes share head)
      float p = __expf(vs);               // logits small: no max-subtract
      denom += p;
      acc += xls * p;
    };
    int i = 0;
    for (; i + 2 <= cnt; i += 2) {
      int s0 = src_s[w][i], s1 = src_s[w][i + 1];
      unsigned int u0 = xlb[(size_t)s0 * 64 + l];  // both issued before use
      unsigned int u1 = xlb[(size_t)s1 * 64 + l];
      edge(i, u0);
      edge(i + 1, u1);
    }
    if (i < cnt) edge(i, xlb[(size_t)src_s[w][i] * 64 + l]);
  }

  f32x2 outp;
  float inv = 1.f / (denom + 1e-16f);
  outp.x = acc.x * inv + bias_o[j0];
  outp.y = acc.y * inv + bias_o[j1];
  // LayerNorm over 128 channels: pair-sum then 64-lane butterfly (per wave)
  float s1 = outp.x + outp.y;
  float s2 = outp.x * outp.x + outp.y * outp.y;
#pragma unroll
  for (int mask = 1; mask <= 32; mask <<= 1) {
    s1 += __shfl_xor(s1, mask);
    s2 += __shfl_xor(s2, mask);
  }
  float mu = s1 * (1.f / 128.f);
  float var = s2 * (1.f / 128.f) - mu * mu;
  float rs = rsqrtf(var + 1e-5f);
  float y0 = lng[j0] * (outp.x - mu) * rs + lnb[j0];
  float y1 = lng[j1] * (outp.y - mu) * rs + lnb[j1];
  float r0 = fmaxf(y0, 0.f) + xin[(size_t)n * HID + j0];
  float r1 = fmaxf(y1, 0.f) + xin[(size_t)n * HID + j1];
  xout[(size_t)n * HID + j0] = r0;
  xout[(size_t)n * HID + j1] = r1;
  xbf_out[(size_t)n * HID + j0] = f2bf(r0);
  xbf_out[(size_t)n * HID + j1] = f2bf(r1);
}

extern "C" void kernel_launch(void* const* d_in, const int* in_sizes, int n_in,
                              void* d_out, int out_size, void* d_ws, size_t ws_size,
                              hipStream_t stream) {
  const float* x0    = (const float*)d_in[0];
  const int*   eidx  = (const int*)d_in[2];
  const float* eattr = (const float*)d_in[3];
  const float* Wt    = (const float*)d_in[4];
  const float* bt    = (const float*)d_in[5];
  const float* Wl    = (const float*)d_in[6];
  const float* bl    = (const float*)d_in[7];
  const float* Wr    = (const float*)d_in[8];
  const float* br    = (const float*)d_in[9];
  const float* We    = (const float*)d_in[10];
  const float* att   = (const float*)d_in[11];
  const float* bo    = (const float*)d_in[12];
  const float* lng   = (const float*)d_in[13];
  const float* lnb   = (const float*)d_in[14];
  float* out = (float*)d_out;
  const int* src = eidx;
  const int* dst = eidx + N_EDGES;

  char* ws = (char*)d_ws;
  size_t off = 0;
  auto alloc = [&](size_t bytes) {
    char* p = ws + off;
    off += (bytes + 255) & ~(size_t)255;
    return p;
  };
  float* Mt   = (float*)alloc((size_t)NLAYERS * EF * HID * 4);
  float* ct   = (float*)alloc((size_t)NLAYERS * HID * 4);
  int* counts = (int*)alloc((size_t)N_NODES * 4);
  int* rowptr = (int*)alloc((size_t)(N_NODES + 1) * 4);
  int* bsum   = (int*)alloc(256 * 4);
  int* fill   = (int*)alloc((size_t)N_NODES * 4);
  int* ssrc   = (int*)alloc((size_t)N_EDGES * 4);
  float* easrt = (float*)alloc((size_t)N_EDGES * EF * 4);
  unsigned short* xlb = (unsigned short*)alloc((size_t)N_NODES * HID * 2);
  unsigned short* xrb = (unsigned short*)alloc((size_t)N_NODES * HID * 2);
  float* xbuf = (float*)alloc((size_t)N_NODES * HID * 4);
  unsigned short* xbf = (unsigned short*)alloc((size_t)N_NODES * HID * 2);
  unsigned short* WTb = (unsigned short*)alloc((size_t)NLAYERS * 2 * HID * HID * 2);

  hipLaunchKernelGGL(k_prep, dim3(26), dim3(256), 0, stream, Wt, bt, We, Mt, ct);
  hipLaunchKernelGGL(k_cvtx, dim3((N_NODES * HID / 8 + 255) / 256), dim3(256), 0, stream, x0, xbf);
  hipLaunchKernelGGL(k_cvtw, dim3((NLAYERS * 2 * HID * HID + 255) / 256), dim3(256), 0, stream, Wl, Wr, WTb);
  hipLaunchKernelGGL(k_zero, dim3(SCAN_BLOCKS), dim3(256), 0, stream, counts, fill);
  hipLaunchKernelGGL(k_hist, dim3((N_EDGES + 255) / 256), dim3(256), 0, stream, dst, counts);
  hipLaunchKernelGGL(k_scan1, dim3(SCAN_BLOCKS), dim3(256), 0, stream, counts, rowptr, bsum);
  hipLaunchKernelGGL(k_scan2, dim3(1), dim3(256), 0, stream, bsum);
  hipLaunchKernelGGL(k_scan3, dim3(SCAN_BLOCKS), dim3(256), 0, stream, rowptr, bsum);
  hipLaunchKernelGGL(k_fill, dim3((N_EDGES + 255) / 256), dim3(256), 0, stream,
                     src, dst, rowptr, fill, ssrc, eattr, easrt);

  for (int l = 0; l < NLAYERS; ++l) {
    const float* xin = (l == 0) ? x0 : (const float*)xbuf;
    float* xout = (l == NLAYERS - 1) ? out : xbuf;
    hipLaunchKernelGGL(k_gemm_mfma, dim3((N_NODES + 63) / 64, 2), dim3(256), 0, stream,
                       xbf, WTb + (size_t)l * 2 * HID * HID, bl + l * HID, br + l * HID, xlb, xrb);
    hipLaunchKernelGGL(k_fused, dim3(N_NODES / 4), dim3(256), 0, stream,
                       xin, (const unsigned int*)xlb, (const unsigned int*)xrb,
                       rowptr, ssrc, easrt,
                       Mt + (size_t)l * EF * HID, ct + l * HID, att + l * HID,
                       bo + l * HID, lng + l * HID, lnb + l * HID, xout, xbf);
  }
}

// Round 8
// 501.698 us; speedup vs baseline: 1.1873x; 1.1616x over previous
//
#include <hip/hip_runtime.h>

#define N_NODES 50000
#define N_EDGES 640000
#define HID 128
#define EF 16
#define NLAYERS 3
#define CHUNK 32
#define SCAN_BLOCKS 196  // ceil(50000/256)

typedef __attribute__((ext_vector_type(8))) short short8;
typedef __attribute__((ext_vector_type(4))) float f32x4;
typedef __attribute__((ext_vector_type(2))) float f32x2;

__device__ __forceinline__ unsigned short f2bf(float f) {
  unsigned int u = __float_as_uint(f);
  u = u + 0x7FFFu + ((u >> 16) & 1u);  // RNE
  return (unsigned short)(u >> 16);
}

// 8-lane butterfly sum via DPP: xor1, xor2 (quad_perm), then half-row mirror.
// Reduces within each aligned group of 8 lanes (one head).
__device__ __forceinline__ float dpp_hadd8(float v) {
  int x;
  x = __builtin_amdgcn_update_dpp(0, __float_as_int(v), 0xB1, 0xF, 0xF, true);
  v += __int_as_float(x);
  x = __builtin_amdgcn_update_dpp(0, __float_as_int(v), 0x4E, 0xF, 0xF, true);
  v += __int_as_float(x);
  x = __builtin_amdgcn_update_dpp(0, __float_as_int(v), 0x141, 0xF, 0xF, true);
  v += __int_as_float(x);
  return v;
}

// channel j = h*16+c -> paired slot: lane l = h*8 + (c&7) holds halves c>>3.
// slot(j) = l*2 + (c>>3). Both of a lane's channels share head h = l>>3.
__device__ __forceinline__ int pslot(int j) {
  return (((j >> 4) * 8 + (j & 7)) << 1) + ((j >> 3) & 1);
}

// Mt[l][k][slot(j)] = sum_i Wt[k,i] * We[l][i,j]   (16x128 per layer, paired cols)
// ct[l][slot(j)]    = sum_i bt[i]  * We[l][i,j]
__global__ __launch_bounds__(256) void k_prep(const float* __restrict__ Wt,
                                              const float* __restrict__ bt,
                                              const float* __restrict__ We,
                                              float* __restrict__ Mt,
                                              float* __restrict__ ct) {
  int id = blockIdx.x * 256 + threadIdx.x;
  const int total = NLAYERS * (EF + 1) * HID;
  if (id >= total) return;
  int l = id / ((EF + 1) * HID);
  int r = id % ((EF + 1) * HID);
  int row = r / HID;
  int j = r % HID;
  const float* Wel = We + l * HID * HID;
  float s = 0.f;
  if (row < EF) {
    const float* wtr = Wt + row * HID;
    for (int i = 0; i < HID; ++i) s += wtr[i] * Wel[i * HID + j];
    Mt[(l * EF + row) * HID + pslot(j)] = s;
  } else {
    for (int i = 0; i < HID; ++i) s += bt[i] * Wel[i * HID + j];
    ct[l * HID + pslot(j)] = s;
  }
}

// x0 (fp32) -> bf16
__global__ __launch_bounds__(256) void k_cvtx(const float* __restrict__ x,
                                              unsigned short* __restrict__ xbf) {
  int id = blockIdx.x * 256 + threadIdx.x;  // one per 8 elements
  const int total = N_NODES * HID / 8;
  if (id >= total) return;
  const float4* p = (const float4*)(x + id * 8);
  float4 a = p[0], b = p[1];
  unsigned short o[8] = {f2bf(a.x), f2bf(a.y), f2bf(a.z), f2bf(a.w),
                         f2bf(b.x), f2bf(b.y), f2bf(b.z), f2bf(b.w)};
  *(uint4*)(xbf + id * 8) = *(uint4*)o;
}

// WT_bf[l][s][n][k] = bf16( W_s[l][k][n] ),  s=0 -> Wl, s=1 -> Wr
__global__ __launch_bounds__(256) void k_cvtw(const float* __restrict__ Wl,
                                              const float* __restrict__ Wr,
                                              unsigned short* __restrict__ WT) {
  int id = blockIdx.x * 256 + threadIdx.x;
  const int total = NLAYERS * 2 * HID * HID;
  if (id >= total) return;
  int k = id & (HID - 1);
  int n = (id >> 7) & (HID - 1);
  int s = (id >> 14) & 1;
  int l = id >> 15;
  const float* W = (s == 0 ? Wl : Wr) + (size_t)l * HID * HID;
  WT[id] = f2bf(W[k * HID + n]);
}

__global__ __launch_bounds__(256) void k_zero(int* __restrict__ counts, int* __restrict__ fill) {
  int id = blockIdx.x * 256 + threadIdx.x;
  if (id < N_NODES) { counts[id] = 0; fill[id] = 0; }
}

__global__ __launch_bounds__(256) void k_hist(const int* __restrict__ dst, int* __restrict__ counts) {
  int e = blockIdx.x * 256 + threadIdx.x;
  if (e < N_EDGES) atomicAdd(&counts[dst[e]], 1);
}

__global__ __launch_bounds__(256) void k_scan1(const int* __restrict__ counts,
                                               int* __restrict__ rowptr,
                                               int* __restrict__ bsum) {
  __shared__ int sc[256];
  int t = threadIdx.x;
  int i = blockIdx.x * 256 + t;
  int v = (i < N_NODES) ? counts[i] : 0;
  sc[t] = v;
  __syncthreads();
  for (int off = 1; off < 256; off <<= 1) {
    int u = 0;
    if (t >= off) u = sc[t - off];
    __syncthreads();
    sc[t] += u;
    __syncthreads();
  }
  if (i < N_NODES) rowptr[i] = sc[t] - v;  // block-local exclusive
  if (t == 255) bsum[blockIdx.x] = sc[255];
}

__global__ __launch_bounds__(256) void k_scan2(int* __restrict__ bsum) {
  __shared__ int sc[256];
  int t = threadIdx.x;
  int v = (t < SCAN_BLOCKS) ? bsum[t] : 0;
  sc[t] = v;
  __syncthreads();
  for (int off = 1; off < 256; off <<= 1) {
    int u = 0;
    if (t >= off) u = sc[t - off];
    __syncthreads();
    sc[t] += u;
    __syncthreads();
  }
  bsum[t] = sc[t] - v;  // exclusive block offsets
}

__global__ __launch_bounds__(256) void k_scan3(int* __restrict__ rowptr, const int* __restrict__ bsum) {
  int t = threadIdx.x;
  int i = blockIdx.x * 256 + t;
  if (i < N_NODES) rowptr[i] += bsum[blockIdx.x];
  if (i == 0) rowptr[N_NODES] = N_EDGES;
}

// Scatter edges into dst-sorted order; also copy edge_attr rows so the hot
// loop reads them fully sequentially (no 2x cacheline over-fetch).
__global__ __launch_bounds__(256) void k_fill(const int* __restrict__ src,
                                              const int* __restrict__ dst,
                                              const int* __restrict__ rowptr,
                                              int* __restrict__ fill,
                                              int* __restrict__ ssrc,
                                              const float* __restrict__ eattr,
                                              float* __restrict__ easrt) {
  int e = blockIdx.x * 256 + threadIdx.x;
  if (e >= N_EDGES) return;
  int d = dst[e];
  int pos = atomicAdd(&fill[d], 1);
  int idx = rowptr[d] + pos;
  ssrc[idx] = src[e];
  const float4* pe = (const float4*)(eattr + (size_t)e * EF);
  float4* po = (float4*)(easrt + (size_t)idx * EF);
#pragma unroll
  for (int q = 0; q < 4; ++q) po[q] = pe[q];
}

// bf16 MFMA node GEMM: out_s = x @ W_s + b_s, channel-PAIRED layout, both
// outputs stored as bf16. For s=1 (xr) the per-layer ct vector is folded
// into the bias so k_fused doesn't need a separate ct read.
__global__ __launch_bounds__(256) void k_gemm_mfma(const unsigned short* __restrict__ xbf,
                                                   const unsigned short* __restrict__ WTl,  // layer base: [2][128][128]
                                                   const float* __restrict__ bl,
                                                   const float* __restrict__ br,
                                                   const float* __restrict__ ctl,  // paired, layer base
                                                   unsigned short* __restrict__ xlb,  // paired bf16
                                                   unsigned short* __restrict__ xrb) {  // paired bf16
  __shared__ short As[64 * 136];
  __shared__ short Bs[128 * 136];
  int t = threadIdx.x;
  int s = blockIdx.y;
  int row0 = blockIdx.x * 64;

  // stage A: 64 rows x 128 bf16, 16B chunks
  const uint4* gx = (const uint4*)xbf;
#pragma unroll
  for (int p = 0; p < 4; ++p) {
    int c = t + p * 256;
    int row = c >> 4, col16 = c & 15;
    int grow = row0 + row;
    if (grow >= N_NODES) grow = N_NODES - 1;
    uint4 v = gx[grow * 16 + col16];
    *(uint4*)(&As[row * 136 + col16 * 8]) = v;
  }
  // stage B: 128 rows (n) x 128 bf16 of WT[s]
  const uint4* gw = (const uint4*)WTl;
#pragma unroll
  for (int p = 0; p < 8; ++p) {
    int c = t + p * 256;
    int row = c >> 4, col16 = c & 15;
    uint4 v = gw[s * 2048 + row * 16 + col16];
    *(uint4*)(&Bs[row * 136 + col16 * 8]) = v;
  }
  __syncthreads();

  int lane = t & 63, w = t >> 6;
  int quad = lane >> 4, lm = lane & 15;
  f32x4 acc[4][2];
#pragma unroll
  for (int mf = 0; mf < 4; ++mf)
#pragma unroll
    for (int nf = 0; nf < 2; ++nf) acc[mf][nf] = (f32x4)(0.f);

#pragma unroll
  for (int ks = 0; ks < 4; ++ks) {
    short8 af[4], bf[2];
#pragma unroll
    for (int mf = 0; mf < 4; ++mf)
      af[mf] = *(short8*)(&As[(mf * 16 + lm) * 136 + ks * 32 + quad * 8]);
#pragma unroll
    for (int nf = 0; nf < 2; ++nf)
      bf[nf] = *(short8*)(&Bs[(w * 32 + nf * 16 + lm) * 136 + ks * 32 + quad * 8]);
#pragma unroll
    for (int mf = 0; mf < 4; ++mf)
#pragma unroll
      for (int nf = 0; nf < 2; ++nf)
        acc[mf][nf] = __builtin_amdgcn_mfma_f32_16x16x32_bf16(af[mf], bf[nf], acc[mf][nf], 0, 0, 0);
  }

  const float* bias = (s == 0) ? bl : br;
  unsigned short* out = (s == 0) ? xlb : xrb;
#pragma unroll
  for (int nf = 0; nf < 2; ++nf) {
    int n = w * 32 + nf * 16 + lm;
    int slot = pslot(n);
    float bv = bias[n] + ((s == 1) ? ctl[slot] : 0.f);
#pragma unroll
    for (int mf = 0; mf < 4; ++mf) {
#pragma unroll
      for (int r = 0; r < 4; ++r) {
        int grow = row0 + mf * 16 + quad * 4 + r;
        if (grow < N_NODES) out[(size_t)grow * HID + slot] = f2bf(acc[mf][nf][r] + bv);
      }
    }
  }
}

// ONE WAVE (64 threads) per destination node, barrier-free. Lane l owns
// channels j0=(l>>3)*16+(l&7) and j0+8 (same head -> one 8-lane DPP reduce
// + one exp per edge). xl gathered as paired bf16 dwords with a depth-4
// software pipeline (4-8 loads in flight) to cover L2/L3 gather latency.
__global__ __launch_bounds__(64) void k_fused(const float* __restrict__ xin,
                                              const unsigned int* __restrict__ xlb,  // paired bf16
                                              const unsigned int* __restrict__ xrb,  // paired bf16 (incl. ct)
                                              const int* __restrict__ rowptr,
                                              const int* __restrict__ ssrc,
                                              const float* __restrict__ easrt,  // dst-sorted [E][16]
                                              const float* __restrict__ Mt,   // paired cols
                                              const float* __restrict__ att,
                                              const float* __restrict__ bias_o,
                                              const float* __restrict__ lng,
                                              const float* __restrict__ lnb,
                                              float* __restrict__ xout,
                                              unsigned short* __restrict__ xbf_out) {
  __shared__ float ea_s[CHUNK][EF];
  __shared__ int src_s[CHUNK];
  int n = blockIdx.x;
  int l = threadIdx.x;  // lane 0..63
  int j0 = (l >> 3) * 16 + (l & 7), j1 = j0 + 8;

  f32x2 mtp[EF];
#pragma unroll
  for (int k = 0; k < EF; ++k) mtp[k] = *(const f32x2*)(&Mt[k * HID + l * 2]);
  unsigned int ur = xrb[(size_t)n * 64 + l];
  f32x2 base;
  base.x = __uint_as_float(ur << 16);
  base.y = __uint_as_float(ur & 0xFFFF0000u);
  f32x2 attp = {att[j0], att[j1]};
  int beg = rowptr[n], end = rowptr[n + 1];

  f32x2 acc = {0.f, 0.f};
  float denom = 0.f;

  for (int c0 = beg; c0 < end; c0 += CHUNK) {
    int cnt = min(CHUNK, end - c0);
    // wave-private staging (single-wave block: no barrier, lgkmcnt orders RAW)
    if (l < cnt) src_s[l] = ssrc[c0 + l];
    for (int q = l; q < cnt * 4; q += 64) {
      int i = q >> 2, part = q & 3;
      *(float4*)(&ea_s[i][part * 4]) =
          *(const float4*)(easrt + (size_t)(c0 + i) * EF + part * 4);
    }

    auto edge = [&](int i, unsigned int u) {
      f32x2 xls;
      xls.x = __uint_as_float(u << 16);
      xls.y = __uint_as_float(u & 0xFFFF0000u);
      f32x2 m = base + xls;
#pragma unroll
      for (int k = 0; k < EF; ++k) m += ea_s[i][k] * mtp[k];
      // leaky_relu(m, 0.2) = 0.6*m + 0.4*|m|
      f32x2 am = {__int_as_float(__float_as_int(m.x) & 0x7FFFFFFF),
                  __int_as_float(__float_as_int(m.y) & 0x7FFFFFFF)};
      m = 0.6f * m + 0.4f * am;
      f32x2 v2 = m * attp;
      float vs = dpp_hadd8(v2.x + v2.y);  // head logit (8 lanes share head)
      float p = __expf(vs);               // logits small: no max-subtract
      denom += p;
      acc += xls * p;
    };

    // depth-4 software pipeline over the gathers
    unsigned int cur[4];
#pragma unroll
    for (int q = 0; q < 4; ++q)
      cur[q] = (q < cnt) ? xlb[(size_t)src_s[q] * 64 + l] : 0u;
    int cnt4 = cnt & ~3;
    for (int i = 0; i < cnt4; i += 4) {
      unsigned int nxt[4];
#pragma unroll
      for (int q = 0; q < 4; ++q) {
        int idx = i + 4 + q;
        nxt[q] = (idx < cnt) ? xlb[(size_t)src_s[idx] * 64 + l] : 0u;
      }
#pragma unroll
      for (int q = 0; q < 4; ++q) edge(i + q, cur[q]);
#pragma unroll
      for (int q = 0; q < 4; ++q) cur[q] = nxt[q];
    }
#pragma unroll
    for (int q = 0; q < 4; ++q)
      if (cnt4 + q < cnt) edge(cnt4 + q, cur[q]);
  }

  f32x2 outp;
  float inv = 1.f / (denom + 1e-16f);
  outp.x = acc.x * inv + bias_o[j0];
  outp.y = acc.y * inv + bias_o[j1];
  // LayerNorm over 128 channels: pair-sum then 64-lane butterfly (single wave)
  float s1 = outp.x + outp.y;
  float s2 = outp.x * outp.x + outp.y * outp.y;
#pragma unroll
  for (int mask = 1; mask <= 32; mask <<= 1) {
    s1 += __shfl_xor(s1, mask);
    s2 += __shfl_xor(s2, mask);
  }
  float mu = s1 * (1.f / 128.f);
  float var = s2 * (1.f / 128.f) - mu * mu;
  float rs = rsqrtf(var + 1e-5f);
  float y0 = lng[j0] * (outp.x - mu) * rs + lnb[j0];
  float y1 = lng[j1] * (outp.y - mu) * rs + lnb[j1];
  float r0 = fmaxf(y0, 0.f) + xin[(size_t)n * HID + j0];
  float r1 = fmaxf(y1, 0.f) + xin[(size_t)n * HID + j1];
  xout[(size_t)n * HID + j0] = r0;
  xout[(size_t)n * HID + j1] = r1;
  xbf_out[(size_t)n * HID + j0] = f2bf(r0);
  xbf_out[(size_t)n * HID + j1] = f2bf(r1);
}

extern "C" void kernel_launch(void* const* d_in, const int* in_sizes, int n_in,
                              void* d_out, int out_size, void* d_ws, size_t ws_size,
                              hipStream_t stream) {
  const float* x0    = (const float*)d_in[0];
  const int*   eidx  = (const int*)d_in[2];
  const float* eattr = (const float*)d_in[3];
  const float* Wt    = (const float*)d_in[4];
  const float* bt    = (const float*)d_in[5];
  const float* Wl    = (const float*)d_in[6];
  const float* bl    = (const float*)d_in[7];
  const float* Wr    = (const float*)d_in[8];
  const float* br    = (const float*)d_in[9];
  const float* We    = (const float*)d_in[10];
  const float* att   = (const float*)d_in[11];
  const float* bo    = (const float*)d_in[12];
  const float* lng   = (const float*)d_in[13];
  const float* lnb   = (const float*)d_in[14];
  float* out = (float*)d_out;
  const int* src = eidx;
  const int* dst = eidx + N_EDGES;

  char* ws = (char*)d_ws;
  size_t off = 0;
  auto alloc = [&](size_t bytes) {
    char* p = ws + off;
    off += (bytes + 255) & ~(size_t)255;
    return p;
  };
  float* Mt   = (float*)alloc((size_t)NLAYERS * EF * HID * 4);
  float* ct   = (float*)alloc((size_t)NLAYERS * HID * 4);
  int* counts = (int*)alloc((size_t)N_NODES * 4);
  int* rowptr = (int*)alloc((size_t)(N_NODES + 1) * 4);
  int* bsum   = (int*)alloc(256 * 4);
  int* fill   = (int*)alloc((size_t)N_NODES * 4);
  int* ssrc   = (int*)alloc((size_t)N_EDGES * 4);
  float* easrt = (float*)alloc((size_t)N_EDGES * EF * 4);
  unsigned short* xlb = (unsigned short*)alloc((size_t)N_NODES * HID * 2);
  unsigned short* xrb = (unsigned short*)alloc((size_t)N_NODES * HID * 2);
  float* xbuf = (float*)alloc((size_t)N_NODES * HID * 4);
  unsigned short* xbf = (unsigned short*)alloc((size_t)N_NODES * HID * 2);
  unsigned short* WTb = (unsigned short*)alloc((size_t)NLAYERS * 2 * HID * HID * 2);

  hipLaunchKernelGGL(k_prep, dim3(26), dim3(256), 0, stream, Wt, bt, We, Mt, ct);
  hipLaunchKernelGGL(k_cvtx, dim3((N_NODES * HID / 8 + 255) / 256), dim3(256), 0, stream, x0, xbf);
  hipLaunchKernelGGL(k_cvtw, dim3((NLAYERS * 2 * HID * HID + 255) / 256), dim3(256), 0, stream, Wl, Wr, WTb);
  hipLaunchKernelGGL(k_zero, dim3(SCAN_BLOCKS), dim3(256), 0, stream, counts, fill);
  hipLaunchKernelGGL(k_hist, dim3((N_EDGES + 255) / 256), dim3(256), 0, stream, dst, counts);
  hipLaunchKernelGGL(k_scan1, dim3(SCAN_BLOCKS), dim3(256), 0, stream, counts, rowptr, bsum);
  hipLaunchKernelGGL(k_scan2, dim3(1), dim3(256), 0, stream, bsum);
  hipLaunchKernelGGL(k_scan3, dim3(SCAN_BLOCKS), dim3(256), 0, stream, rowptr, bsum);
  hipLaunchKernelGGL(k_fill, dim3((N_EDGES + 255) / 256), dim3(256), 0, stream,
                     src, dst, rowptr, fill, ssrc, eattr, easrt);

  for (int l = 0; l < NLAYERS; ++l) {
    const float* xin = (l == 0) ? x0 : (const float*)xbuf;
    float* xout = (l == NLAYERS - 1) ? out : xbuf;
    hipLaunchKernelGGL(k_gemm_mfma, dim3((N_NODES + 63) / 64, 2), dim3(256), 0, stream,
                       xbf, WTb + (size_t)l * 2 * HID * HID, bl + l * HID, br + l * HID,
                       ct + (size_t)l * HID, xlb, xrb);
    hipLaunchKernelGGL(k_fused, dim3(N_NODES), dim3(64), 0, stream,
                       xin, (const unsigned int*)xlb, (const unsigned int*)xrb,
                       rowptr, ssrc, easrt,
                       Mt + (size_t)l * EF * HID, att + l * HID,
                       bo + l * HID, lng + l * HID, lnb + l * HID, xout, xbf);
  }
}

// Round 9
// 493.664 us; speedup vs baseline: 1.2066x; 1.0163x over previous
//
#include <hip/hip_runtime.h>

#define N_NODES 50000
#define N_EDGES 640000
#define HID 128
#define EF 16
#define NLAYERS 3
#define CHUNK 32
#define SCAN_BLOCKS 196  // ceil(50000/256)

typedef __attribute__((ext_vector_type(8))) short short8;
typedef __attribute__((ext_vector_type(4))) float f32x4;
typedef __attribute__((ext_vector_type(2))) float f32x2;

__device__ __forceinline__ unsigned short f2bf(float f) {
  unsigned int u = __float_as_uint(f);
  u = u + 0x7FFFu + ((u >> 16) & 1u);  // RNE
  return (unsigned short)(u >> 16);
}

// 8-lane butterfly sum via DPP: xor1, xor2 (quad_perm), then half-row mirror.
__device__ __forceinline__ float dpp_hadd8(float v) {
  int x;
  x = __builtin_amdgcn_update_dpp(0, __float_as_int(v), 0xB1, 0xF, 0xF, true);
  v += __int_as_float(x);
  x = __builtin_amdgcn_update_dpp(0, __float_as_int(v), 0x4E, 0xF, 0xF, true);
  v += __int_as_float(x);
  x = __builtin_amdgcn_update_dpp(0, __float_as_int(v), 0x141, 0xF, 0xF, true);
  v += __int_as_float(x);
  return v;
}

// channel j = h*16+c -> paired slot: lane l = h*8 + (c&7) holds halves c>>3.
__device__ __forceinline__ int pslot(int j) {
  return (((j >> 4) * 8 + (j & 7)) << 1) + ((j >> 3) & 1);
}

// Fused setup: blocks [0,26) k_prep, [26,410) cvtw, [410,3535) cvtx.
__global__ __launch_bounds__(256) void k_setup(const float* __restrict__ Wt,
                                               const float* __restrict__ bt,
                                               const float* __restrict__ We,
                                               const float* __restrict__ Wl,
                                               const float* __restrict__ Wr,
                                               const float* __restrict__ x,
                                               float* __restrict__ Mt,
                                               float* __restrict__ ct,
                                               unsigned short* __restrict__ WT,
                                               unsigned short* __restrict__ xbf) {
  int b = blockIdx.x, t = threadIdx.x;
  if (b < 26) {
    int id = b * 256 + t;
    const int total = NLAYERS * (EF + 1) * HID;
    if (id >= total) return;
    int l = id / ((EF + 1) * HID);
    int r = id % ((EF + 1) * HID);
    int row = r / HID;
    int j = r % HID;
    const float* Wel = We + l * HID * HID;
    float s = 0.f;
    if (row < EF) {
      const float* wtr = Wt + row * HID;
      for (int i = 0; i < HID; ++i) s += wtr[i] * Wel[i * HID + j];
      Mt[(l * EF + row) * HID + pslot(j)] = s;
    } else {
      for (int i = 0; i < HID; ++i) s += bt[i] * Wel[i * HID + j];
      ct[l * HID + pslot(j)] = s;
    }
  } else if (b < 410) {
    int id = (b - 26) * 256 + t;  // exactly NLAYERS*2*128*128 = 98304
    int k = id & (HID - 1);
    int n = (id >> 7) & (HID - 1);
    int s = (id >> 14) & 1;
    int l = id >> 15;
    const float* W = (s == 0 ? Wl : Wr) + (size_t)l * HID * HID;
    WT[id] = f2bf(W[k * HID + n]);
  } else {
    int id = (b - 410) * 256 + t;  // exactly N_NODES*HID/8 = 800000
    const float4* p = (const float4*)(x + (size_t)id * 8);
    float4 a = p[0], bb = p[1];
    unsigned short o[8] = {f2bf(a.x), f2bf(a.y), f2bf(a.z), f2bf(a.w),
                           f2bf(bb.x), f2bf(bb.y), f2bf(bb.z), f2bf(bb.w)};
    *(uint4*)(xbf + (size_t)id * 8) = *(uint4*)o;
  }
}

__global__ __launch_bounds__(256) void k_hist(const int* __restrict__ dst, int* __restrict__ counts) {
  int e = blockIdx.x * 256 + threadIdx.x;
  if (e < N_EDGES) atomicAdd(&counts[dst[e]], 1);
}

__global__ __launch_bounds__(256) void k_scan1(const int* __restrict__ counts,
                                               int* __restrict__ rowptr,
                                               int* __restrict__ bsum) {
  __shared__ int sc[256];
  int t = threadIdx.x;
  int i = blockIdx.x * 256 + t;
  int v = (i < N_NODES) ? counts[i] : 0;
  sc[t] = v;
  __syncthreads();
  for (int off = 1; off < 256; off <<= 1) {
    int u = 0;
    if (t >= off) u = sc[t - off];
    __syncthreads();
    sc[t] += u;
    __syncthreads();
  }
  if (i < N_NODES) rowptr[i] = sc[t] - v;  // block-local exclusive
  if (t == 255) bsum[blockIdx.x] = sc[255];
}

__global__ __launch_bounds__(256) void k_scan2(int* __restrict__ bsum) {
  __shared__ int sc[256];
  int t = threadIdx.x;
  int v = (t < SCAN_BLOCKS) ? bsum[t] : 0;
  sc[t] = v;
  __syncthreads();
  for (int off = 1; off < 256; off <<= 1) {
    int u = 0;
    if (t >= off) u = sc[t - off];
    __syncthreads();
    sc[t] += u;
    __syncthreads();
  }
  bsum[t] = sc[t] - v;  // exclusive block offsets
}

__global__ __launch_bounds__(256) void k_scan3(int* __restrict__ rowptr, const int* __restrict__ bsum) {
  int t = threadIdx.x;
  int i = blockIdx.x * 256 + t;
  if (i < N_NODES) rowptr[i] += bsum[blockIdx.x];
  if (i == 0) rowptr[N_NODES] = N_EDGES;
}

// Scatter edges into dst-sorted order; ssrc stores src*64 (dword row offset)
// so the hot loop's gather address is a single lshl_add. Also copy edge_attr.
__global__ __launch_bounds__(256) void k_fill(const int* __restrict__ src,
                                              const int* __restrict__ dst,
                                              const int* __restrict__ rowptr,
                                              int* __restrict__ fill,
                                              int* __restrict__ ssrc,
                                              const float* __restrict__ eattr,
                                              float* __restrict__ easrt) {
  int e = blockIdx.x * 256 + threadIdx.x;
  if (e >= N_EDGES) return;
  int d = dst[e];
  int pos = atomicAdd(&fill[d], 1);
  int idx = rowptr[d] + pos;
  ssrc[idx] = src[e] << 6;
  const float4* pe = (const float4*)(eattr + (size_t)e * EF);
  float4* po = (float4*)(easrt + (size_t)idx * EF);
#pragma unroll
  for (int q = 0; q < 4; ++q) po[q] = pe[q];
}

// bf16 MFMA node GEMM: out_s = x @ W_s + b_s, channel-PAIRED layout, bf16 out.
// s=1 (xr) folds ct into the bias.
__global__ __launch_bounds__(256) void k_gemm_mfma(const unsigned short* __restrict__ xbf,
                                                   const unsigned short* __restrict__ WTl,
                                                   const float* __restrict__ bl,
                                                   const float* __restrict__ br,
                                                   const float* __restrict__ ctl,
                                                   unsigned short* __restrict__ xlb,
                                                   unsigned short* __restrict__ xrb) {
  __shared__ short As[64 * 136];
  __shared__ short Bs[128 * 136];
  int t = threadIdx.x;
  int s = blockIdx.y;
  int row0 = blockIdx.x * 64;

  const uint4* gx = (const uint4*)xbf;
#pragma unroll
  for (int p = 0; p < 4; ++p) {
    int c = t + p * 256;
    int row = c >> 4, col16 = c & 15;
    int grow = row0 + row;
    if (grow >= N_NODES) grow = N_NODES - 1;
    uint4 v = gx[grow * 16 + col16];
    *(uint4*)(&As[row * 136 + col16 * 8]) = v;
  }
  const uint4* gw = (const uint4*)WTl;
#pragma unroll
  for (int p = 0; p < 8; ++p) {
    int c = t + p * 256;
    int row = c >> 4, col16 = c & 15;
    uint4 v = gw[s * 2048 + row * 16 + col16];
    *(uint4*)(&Bs[row * 136 + col16 * 8]) = v;
  }
  __syncthreads();

  int lane = t & 63, w = t >> 6;
  int quad = lane >> 4, lm = lane & 15;
  f32x4 acc[4][2];
#pragma unroll
  for (int mf = 0; mf < 4; ++mf)
#pragma unroll
    for (int nf = 0; nf < 2; ++nf) acc[mf][nf] = (f32x4)(0.f);

#pragma unroll
  for (int ks = 0; ks < 4; ++ks) {
    short8 af[4], bf[2];
#pragma unroll
    for (int mf = 0; mf < 4; ++mf)
      af[mf] = *(short8*)(&As[(mf * 16 + lm) * 136 + ks * 32 + quad * 8]);
#pragma unroll
    for (int nf = 0; nf < 2; ++nf)
      bf[nf] = *(short8*)(&Bs[(w * 32 + nf * 16 + lm) * 136 + ks * 32 + quad * 8]);
#pragma unroll
    for (int mf = 0; mf < 4; ++mf)
#pragma unroll
      for (int nf = 0; nf < 2; ++nf)
        acc[mf][nf] = __builtin_amdgcn_mfma_f32_16x16x32_bf16(af[mf], bf[nf], acc[mf][nf], 0, 0, 0);
  }

  const float* bias = (s == 0) ? bl : br;
  unsigned short* out = (s == 0) ? xlb : xrb;
#pragma unroll
  for (int nf = 0; nf < 2; ++nf) {
    int n = w * 32 + nf * 16 + lm;
    int slot = pslot(n);
    float bv = bias[n] + ((s == 1) ? ctl[slot] : 0.f);
#pragma unroll
    for (int mf = 0; mf < 4; ++mf) {
#pragma unroll
      for (int r = 0; r < 4; ++r) {
        int grow = row0 + mf * 16 + quad * 4 + r;
        if (grow < N_NODES) out[(size_t)grow * HID + slot] = f2bf(acc[mf][nf][r] + bv);
      }
    }
  }
}

// ONE WAVE per destination node, barrier-free. Lane l owns channels
// j0=(l>>3)*16+(l&7), j0+8 (same head). Depth-4 pipelined unconditional
// gathers (src_s padded with 8 safe entries), ea via explicit b128 LDS
// reads, exp2 with log2e folded into att.
__global__ __launch_bounds__(64) void k_fused(const float* __restrict__ xin,
                                              const unsigned int* __restrict__ xlb,  // paired bf16
                                              const unsigned int* __restrict__ xrb,  // paired bf16 (incl. ct)
                                              const int* __restrict__ rowptr,
                                              const int* __restrict__ ssrc,  // src*64
                                              const float* __restrict__ easrt,  // dst-sorted [E][16]
                                              const float* __restrict__ Mt,   // paired cols
                                              const float* __restrict__ att,
                                              const float* __restrict__ bias_o,
                                              const float* __restrict__ lng,
                                              const float* __restrict__ lnb,
                                              float* __restrict__ xout,
                                              unsigned short* __restrict__ xbf_out) {
  __shared__ __align__(16) float ea_s[CHUNK][EF];
  __shared__ int src_s[CHUNK + 8];
  int n = blockIdx.x;
  int l = threadIdx.x;  // lane 0..63
  int j0 = (l >> 3) * 16 + (l & 7), j1 = j0 + 8;

  f32x2 mtp[EF];
#pragma unroll
  for (int k = 0; k < EF; ++k) mtp[k] = *(const f32x2*)(&Mt[k * HID + l * 2]);
  unsigned int ur = xrb[(size_t)n * 64 + l];
  f32x2 base;
  base.x = __uint_as_float(ur << 16);
  base.y = __uint_as_float(ur & 0xFFFF0000u);
  const float LOG2E = 1.44269504088896340736f;
  f32x2 attp = {att[j0] * LOG2E, att[j1] * LOG2E};
  int beg = rowptr[n], end = rowptr[n + 1];

  f32x2 acc = {0.f, 0.f};
  float denom = 0.f;

  for (int c0 = beg; c0 < end; c0 += CHUNK) {
    int cnt = min(CHUNK, end - c0);
    // wave-private staging (single-wave block: no barrier, lgkmcnt orders RAW)
    if (l < cnt) src_s[l] = ssrc[c0 + l];
    if (l < 8) src_s[cnt + l] = 0;  // pad -> unconditional pipelined loads
    for (int q = l; q < cnt * 4; q += 64) {
      int i = q >> 2, part = q & 3;
      *(float4*)(&ea_s[i][part * 4]) =
          *(const float4*)(easrt + (size_t)(c0 + i) * EF + part * 4);
    }

    auto edge = [&](int i, unsigned int u) {
      f32x2 xls;
      xls.x = __uint_as_float(u << 16);
      xls.y = __uint_as_float(u & 0xFFFF0000u);
      f32x2 m = base + xls;
      const f32x4* er = (const f32x4*)(&ea_s[i][0]);
      f32x4 e0 = er[0], e1 = er[1], e2 = er[2], e3 = er[3];  // 4x ds_read_b128
#pragma unroll
      for (int k = 0; k < 4; ++k) m += e0[k] * mtp[k];
#pragma unroll
      for (int k = 0; k < 4; ++k) m += e1[k] * mtp[4 + k];
#pragma unroll
      for (int k = 0; k < 4; ++k) m += e2[k] * mtp[8 + k];
#pragma unroll
      for (int k = 0; k < 4; ++k) m += e3[k] * mtp[12 + k];
      // leaky_relu(m, 0.2) = 0.6*m + 0.4*|m|
      f32x2 am = {__int_as_float(__float_as_int(m.x) & 0x7FFFFFFF),
                  __int_as_float(__float_as_int(m.y) & 0x7FFFFFFF)};
      m = 0.6f * m + 0.4f * am;
      f32x2 v2 = m * attp;
      float vs = dpp_hadd8(v2.x + v2.y);  // head logit*log2e (8 lanes/head)
      float p = exp2f(vs);                // logits small: no max-subtract
      denom += p;
      acc += xls * p;
    };

    // depth-4 software pipeline, unconditional loads (pad covers overrun)
    unsigned int cur[4];
#pragma unroll
    for (int q = 0; q < 4; ++q) cur[q] = xlb[src_s[q] + l];
    int cnt4 = cnt & ~3;
    for (int i = 0; i < cnt4; i += 4) {
      unsigned int nxt[4];
#pragma unroll
      for (int q = 0; q < 4; ++q) nxt[q] = xlb[src_s[i + 4 + q] + l];
#pragma unroll
      for (int q = 0; q < 4; ++q) edge(i + q, cur[q]);
#pragma unroll
      for (int q = 0; q < 4; ++q) cur[q] = nxt[q];
    }
#pragma unroll
    for (int q = 0; q < 4; ++q)
      if (cnt4 + q < cnt) edge(cnt4 + q, cur[q]);
  }

  f32x2 outp;
  float inv = 1.f / (denom + 1e-16f);
  outp.x = acc.x * inv + bias_o[j0];
  outp.y = acc.y * inv + bias_o[j1];
  // LayerNorm over 128 channels: pair-sum then 64-lane butterfly (single wave)
  float s1 = outp.x + outp.y;
  float s2 = outp.x * outp.x + outp.y * outp.y;
#pragma unroll
  for (int mask = 1; mask <= 32; mask <<= 1) {
    s1 += __shfl_xor(s1, mask);
    s2 += __shfl_xor(s2, mask);
  }
  float mu = s1 * (1.f / 128.f);
  float var = s2 * (1.f / 128.f) - mu * mu;
  float rs = rsqrtf(var + 1e-5f);
  float y0 = lng[j0] * (outp.x - mu) * rs + lnb[j0];
  float y1 = lng[j1] * (outp.y - mu) * rs + lnb[j1];
  float r0 = fmaxf(y0, 0.f) + xin[(size_t)n * HID + j0];
  float r1 = fmaxf(y1, 0.f) + xin[(size_t)n * HID + j1];
  xout[(size_t)n * HID + j0] = r0;
  xout[(size_t)n * HID + j1] = r1;
  xbf_out[(size_t)n * HID + j0] = f2bf(r0);
  xbf_out[(size_t)n * HID + j1] = f2bf(r1);
}

extern "C" void kernel_launch(void* const* d_in, const int* in_sizes, int n_in,
                              void* d_out, int out_size, void* d_ws, size_t ws_size,
                              hipStream_t stream) {
  const float* x0    = (const float*)d_in[0];
  const int*   eidx  = (const int*)d_in[2];
  const float* eattr = (const float*)d_in[3];
  const float* Wt    = (const float*)d_in[4];
  const float* bt    = (const float*)d_in[5];
  const float* Wl    = (const float*)d_in[6];
  const float* bl    = (const float*)d_in[7];
  const float* Wr    = (const float*)d_in[8];
  const float* br    = (const float*)d_in[9];
  const float* We    = (const float*)d_in[10];
  const float* att   = (const float*)d_in[11];
  const float* bo    = (const float*)d_in[12];
  const float* lng   = (const float*)d_in[13];
  const float* lnb   = (const float*)d_in[14];
  float* out = (float*)d_out;
  const int* src = eidx;
  const int* dst = eidx + N_EDGES;

  char* ws = (char*)d_ws;
  size_t off = 0;
  auto alloc = [&](size_t bytes) {
    char* p = ws + off;
    off += (bytes + 255) & ~(size_t)255;
    return p;
  };
  // counts & fill adjacent -> one memset clears both
  int* counts = (int*)alloc((size_t)N_NODES * 4);
  int* fill   = (int*)((char*)counts + (size_t)N_NODES * 4);  // same 256-pad block? no:
  // allocate fill explicitly right after counts
  fill = (int*)alloc((size_t)N_NODES * 4);
  float* Mt   = (float*)alloc((size_t)NLAYERS * EF * HID * 4);
  float* ct   = (float*)alloc((size_t)NLAYERS * HID * 4);
  int* rowptr = (int*)alloc((size_t)(N_NODES + 1) * 4);
  int* bsum   = (int*)alloc(256 * 4);
  int* ssrc   = (int*)alloc((size_t)N_EDGES * 4);
  float* easrt = (float*)alloc((size_t)N_EDGES * EF * 4);
  unsigned short* xlb = (unsigned short*)alloc((size_t)N_NODES * HID * 2);
  unsigned short* xrb = (unsigned short*)alloc((size_t)N_NODES * HID * 2);
  float* xbuf = (float*)alloc((size_t)N_NODES * HID * 4);
  unsigned short* xbf = (unsigned short*)alloc((size_t)N_NODES * HID * 2);
  unsigned short* WTb = (unsigned short*)alloc((size_t)NLAYERS * 2 * HID * HID * 2);

  // clear counts + fill in one async memset (covers the 256B pad between them)
  hipMemsetAsync(counts, 0, (char*)(fill + N_NODES) - (char*)counts, stream);

  hipLaunchKernelGGL(k_setup, dim3(3535), dim3(256), 0, stream,
                     Wt, bt, We, Wl, Wr, x0, Mt, ct, WTb, xbf);
  hipLaunchKernelGGL(k_hist, dim3((N_EDGES + 255) / 256), dim3(256), 0, stream, dst, counts);
  hipLaunchKernelGGL(k_scan1, dim3(SCAN_BLOCKS), dim3(256), 0, stream, counts, rowptr, bsum);
  hipLaunchKernelGGL(k_scan2, dim3(1), dim3(256), 0, stream, bsum);
  hipLaunchKernelGGL(k_scan3, dim3(SCAN_BLOCKS), dim3(256), 0, stream, rowptr, bsum);
  hipLaunchKernelGGL(k_fill, dim3((N_EDGES + 255) / 256), dim3(256), 0, stream,
                     src, dst, rowptr, fill, ssrc, eattr, easrt);

  for (int l = 0; l < NLAYERS; ++l) {
    const float* xin = (l == 0) ? x0 : (const float*)xbuf;
    float* xout = (l == NLAYERS - 1) ? out : xbuf;
    hipLaunchKernelGGL(k_gemm_mfma, dim3((N_NODES + 63) / 64, 2), dim3(256), 0, stream,
                       xbf, WTb + (size_t)l * 2 * HID * HID, bl + l * HID, br + l * HID,
                       ct + (size_t)l * HID, xlb, xrb);
    hipLaunchKernelGGL(k_fused, dim3(N_NODES), dim3(64), 0, stream,
                       xin, (const unsigned int*)xlb, (const unsigned int*)xrb,
                       rowptr, ssrc, easrt,
                       Mt + (size_t)l * EF * HID, att + l * HID,
                       bo + l * HID, lng + l * HID, lnb + l * HID, xout, xbf);
  }
}